// Round 1
// baseline (266.708 us; speedup 1.0000x reference)
//
#include <hip/hip_runtime.h>
#include <hip/hip_bf16.h>

#define DIMN 2048
#define NH 16
#define HD 128
#define BSZ 2
#define SEQ 2048
#define ROWS (BSZ*SEQ)   // 4096

typedef short short8 __attribute__((ext_vector_type(8)));
typedef float f32x4 __attribute__((ext_vector_type(4)));

__device__ __forceinline__ unsigned short f2bf(float f) {
    __hip_bfloat16 h = __float2bfloat16(f);
    unsigned short u; __builtin_memcpy(&u, &h, 2); return u;
}
__device__ __forceinline__ float bf2f(unsigned short u) {
    unsigned x = ((unsigned)u) << 16; float f; __builtin_memcpy(&f, &x, 4); return f;
}

__device__ __forceinline__ void gld_lds16(const void* g, void* l) {
    __builtin_amdgcn_global_load_lds(
        (const __attribute__((address_space(1))) void*)g,
        (__attribute__((address_space(3))) void*)l, 16, 0, 0);
}

// ---------------- f32 -> bf16 convert ----------------
__global__ void cvt_kernel(const float* __restrict__ in, unsigned short* __restrict__ out, int n) {
    int i = (blockIdx.x * 256 + threadIdx.x) * 4;
    if (i >= n) return;
    float4 v = *(const float4*)(in + i);
    ushort4 o;
    o.x = f2bf(v.x); o.y = f2bf(v.y); o.z = f2bf(v.z); o.w = f2bf(v.w);
    *(ushort4*)(out + i) = o;
}

// ---------------- GEMM core: C[m][n] = sum_k A[m][k]*B[n][k] (+bias) ----------------
// 256 threads, 4 waves in 2x2 quadrants, 128x128 tile, BK=64, 16x16x32 bf16 MFMA.
// A,B,C,bias pointers are pre-offset to this block's tile origin.
template<int OUT_BF16, int HAS_BIAS>
__device__ __forceinline__ void gemm_tile_core(
    const unsigned short* __restrict__ A, int lda,
    const unsigned short* __restrict__ B, int ldb,
    const float* __restrict__ bias,
    void* __restrict__ Cptr, int ldc, int K)
{
    __shared__ __align__(16) unsigned short As[128 * 64];
    __shared__ __align__(16) unsigned short Bs[128 * 64];

    const int t  = threadIdx.x;
    const int l  = t & 63;
    const int w  = t >> 6;
    const int wr = w >> 1, wc = w & 1;
    const int fr = l & 15, fq = l >> 4;

    f32x4 acc[4][4] = {};

    const int srow = t >> 3;        // 0..31, +32 per round
    const int scol = (t & 7) * 8;   // element offset in k

    for (int k0 = 0; k0 < K; k0 += 64) {
        __syncthreads();
        #pragma unroll
        for (int r = 0; r < 4; ++r) {
            gld_lds16(A + (size_t)(r * 32 + srow) * lda + k0 + scol, &As[(r * 32 + srow) * 64 + scol]);
            gld_lds16(B + (size_t)(r * 32 + srow) * ldb + k0 + scol, &Bs[(r * 32 + srow) * 64 + scol]);
        }
        __syncthreads();
        #pragma unroll
        for (int kk = 0; kk < 2; ++kk) {
            short8 a[4], b[4];
            #pragma unroll
            for (int mi = 0; mi < 4; ++mi)
                a[mi] = *(const short8*)&As[(wr * 64 + mi * 16 + fr) * 64 + kk * 32 + fq * 8];
            #pragma unroll
            for (int ni = 0; ni < 4; ++ni)
                b[ni] = *(const short8*)&Bs[(wc * 64 + ni * 16 + fr) * 64 + kk * 32 + fq * 8];
            #pragma unroll
            for (int mi = 0; mi < 4; ++mi)
                #pragma unroll
                for (int ni = 0; ni < 4; ++ni)
                    acc[mi][ni] = __builtin_amdgcn_mfma_f32_16x16x32_bf16(a[mi], b[ni], acc[mi][ni], 0, 0, 0);
        }
    }

    #pragma unroll
    for (int mi = 0; mi < 4; ++mi) {
        #pragma unroll
        for (int ni = 0; ni < 4; ++ni) {
            #pragma unroll
            for (int j = 0; j < 4; ++j) {
                int rr = wr * 64 + mi * 16 + fq * 4 + j;
                int cc = wc * 64 + ni * 16 + fr;
                float v = acc[mi][ni][j];
                if (HAS_BIAS) v += bias[cc];
                if (OUT_BF16) ((unsigned short*)Cptr)[(size_t)rr * ldc + cc] = f2bf(v);
                else          ((float*)Cptr)[(size_t)rr * ldc + cc] = v;
            }
        }
    }
}

template<int OUT_BF16, int HAS_BIAS>
__global__ __launch_bounds__(256) void gemm_bt(
    const unsigned short* __restrict__ A, const unsigned short* __restrict__ B,
    const float* __restrict__ bias, void* __restrict__ C,
    int lda, int ldb, int ldc, int K)
{
    const int n0 = blockIdx.x * 128;
    const int m0 = blockIdx.y * 128;
    const unsigned short* Ab = A + (size_t)m0 * lda;
    const unsigned short* Bb = B + (size_t)n0 * ldb;
    const float* biasb = HAS_BIAS ? bias + n0 : nullptr;
    void* Cb = OUT_BF16 ? (void*)((unsigned short*)C + (size_t)m0 * ldc + n0)
                        : (void*)((float*)C + (size_t)m0 * ldc + n0);
    gemm_tile_core<OUT_BF16, HAS_BIAS>(Ab, lda, Bb, ldb, biasb, Cb, ldc, K);
}

// ---------------- per-head Q @ M2^T : attn[s][d2] = sum_d1 Q[s][d1] * M2[d2][d1] ----------------
__global__ __launch_bounds__(256) void qm_gemm(
    const unsigned short* __restrict__ Q, const unsigned short* __restrict__ M2,
    unsigned short* __restrict__ attn)
{
    const int mt = blockIdx.x;  // 0..31 (row tiles of 128 over 4096 rows)
    const int h  = blockIdx.y;  // 0..15
    const int b  = mt >> 4;
    const unsigned short* A = Q + (size_t)(mt * 128) * DIMN + h * HD;
    const unsigned short* B = M2 + (size_t)(b * NH + h) * HD * HD;
    unsigned short* C = attn + (size_t)(mt * 128) * DIMN + h * HD;
    gemm_tile_core<1, 0>(A, DIMN, B, HD, nullptr, C, DIMN, HD);
}

// ---------------- RoPE in place on Q and K ----------------
__global__ void rope_kernel(unsigned short* __restrict__ Q, unsigned short* __restrict__ K,
                            const float* __restrict__ fcos, const float* __restrict__ fsin)
{
    int idx = blockIdx.x * 256 + threadIdx.x;   // ROWS*1024
    int row = idx >> 10, pr = idx & 1023;
    int s = row & (SEQ - 1);
    int i = pr & 63;
    float c  = fcos[s * 64 + i];
    float sn = fsin[s * 64 + i];
    size_t off = (size_t)row * DIMN + ((pr >> 6) << 7) + i * 2;

    unsigned uq = *(const unsigned*)(Q + off);
    float q0 = bf2f((unsigned short)(uq & 0xffff)), q1 = bf2f((unsigned short)(uq >> 16));
    unsigned oq = (unsigned)f2bf(q0 * c - q1 * sn) | ((unsigned)f2bf(q0 * sn + q1 * c) << 16);
    *(unsigned*)(Q + off) = oq;

    unsigned uk = *(const unsigned*)(K + off);
    float k0 = bf2f((unsigned short)(uk & 0xffff)), k1 = bf2f((unsigned short)(uk >> 16));
    unsigned ok = (unsigned)f2bf(k0 * c - k1 * sn) | ((unsigned)f2bf(k0 * sn + k1 * c) << 16);
    *(unsigned*)(K + off) = ok;
}

// ---------------- K^T V partials: part[bh][ks][d2][d1] = sum_{s in split} V[s][d2]*K[s][d1] ----------------
__global__ __launch_bounds__(256) void ktv_kernel(
    const unsigned short* __restrict__ Kb, const unsigned short* __restrict__ Vb,
    float* __restrict__ part)
{
    const int ks = blockIdx.x;  // 0..7
    const int bh = blockIdx.y;  // 0..31
    const int b = bh >> 4, h = bh & 15;
    const unsigned short* Kbase = Kb + (size_t)(b * SEQ + ks * 256) * DIMN + h * HD;
    const unsigned short* Vbase = Vb + (size_t)(b * SEQ + ks * 256) * DIMN + h * HD;

    __shared__ __align__(16) unsigned short Ks_[64 * 128];
    __shared__ __align__(16) unsigned short Vs_[64 * 128];

    const int t  = threadIdx.x;
    const int l  = t & 63;
    const int w  = t >> 6;
    const int wr = w >> 1, wc = w & 1;
    const int fr = l & 15, fq = l >> 4;

    f32x4 acc[4][4] = {};

    const int srow = t >> 4;        // 0..15, +16 per round
    const int scol = (t & 15) * 8;  // element offset within 128

    for (int sc = 0; sc < 4; ++sc) {
        __syncthreads();
        #pragma unroll
        for (int r = 0; r < 4; ++r) {
            gld_lds16(Kbase + (size_t)(sc * 64 + r * 16 + srow) * DIMN + scol, &Ks_[(r * 16 + srow) * 128 + scol]);
            gld_lds16(Vbase + (size_t)(sc * 64 + r * 16 + srow) * DIMN + scol, &Vs_[(r * 16 + srow) * 128 + scol]);
        }
        __syncthreads();
        #pragma unroll
        for (int kk = 0; kk < 2; ++kk) {
            short8 a[4], bb[4];
            #pragma unroll
            for (int mi = 0; mi < 4; ++mi)
                #pragma unroll
                for (int i = 0; i < 8; ++i)
                    a[mi][i] = (short)Vs_[(kk * 32 + fq * 8 + i) * 128 + wr * 64 + mi * 16 + fr];
            #pragma unroll
            for (int ni = 0; ni < 4; ++ni)
                #pragma unroll
                for (int i = 0; i < 8; ++i)
                    bb[ni][i] = (short)Ks_[(kk * 32 + fq * 8 + i) * 128 + wc * 64 + ni * 16 + fr];
            #pragma unroll
            for (int mi = 0; mi < 4; ++mi)
                #pragma unroll
                for (int ni = 0; ni < 4; ++ni)
                    acc[mi][ni] = __builtin_amdgcn_mfma_f32_16x16x32_bf16(a[mi], bb[ni], acc[mi][ni], 0, 0, 0);
        }
    }

    float* base = part + ((size_t)bh * 8 + ks) * 16384;
    #pragma unroll
    for (int mi = 0; mi < 4; ++mi)
        #pragma unroll
        for (int ni = 0; ni < 4; ++ni)
            #pragma unroll
            for (int j = 0; j < 4; ++j)
                base[(wr * 64 + mi * 16 + fq * 4 + j) * 128 + wc * 64 + ni * 16 + fr] = acc[mi][ni][j];
}

// ---------------- reduce partials, scale, -> bf16 M2[bh][d2][d1] ----------------
__global__ void ktv_reduce(const float* __restrict__ part, unsigned short* __restrict__ M2) {
    int idx = blockIdx.x * 256 + threadIdx.x;  // 32*16384
    int bh = idx >> 14, rem = idx & 16383;
    const float* p = part + ((size_t)bh * 8) * 16384 + rem;
    float s = 0.f;
    #pragma unroll
    for (int k = 0; k < 8; ++k) s += p[(size_t)k * 16384];
    M2[idx] = f2bf(s * 0.08838834764831845f);  // 1/sqrt(128)
}

extern "C" void kernel_launch(void* const* d_in, const int* in_sizes, int n_in,
                              void* d_out, int out_size, void* d_ws, size_t ws_size,
                              hipStream_t stream) {
    const float* x    = (const float*)d_in[0];
    const float* fcos = (const float*)d_in[1];
    const float* fsin = (const float*)d_in[2];
    const float* wq   = (const float*)d_in[3];
    const float* bq   = (const float*)d_in[4];
    const float* wk   = (const float*)d_in[5];
    const float* bk   = (const float*)d_in[6];
    const float* wv   = (const float*)d_in[7];
    const float* bv   = (const float*)d_in[8];
    const float* wo   = (const float*)d_in[9];
    const float* bo   = (const float*)d_in[10];
    float* out = (float*)d_out;

    char* ws = (char*)d_ws;
    size_t off = 0;
    auto alloc = [&](size_t bytes) { char* p = ws + off; off += (bytes + 255) & ~(size_t)255; return p; };

    unsigned short* Xb   = (unsigned short*)alloc((size_t)ROWS * DIMN * 2);
    unsigned short* Wq   = (unsigned short*)alloc((size_t)DIMN * DIMN * 2);
    unsigned short* Wk   = (unsigned short*)alloc((size_t)DIMN * DIMN * 2);
    unsigned short* Wv   = (unsigned short*)alloc((size_t)DIMN * DIMN * 2);
    unsigned short* Wo   = (unsigned short*)alloc((size_t)DIMN * DIMN * 2);
    unsigned short* Qb   = (unsigned short*)alloc((size_t)ROWS * DIMN * 2);
    unsigned short* Kb   = (unsigned short*)alloc((size_t)ROWS * DIMN * 2);
    unsigned short* Vb   = (unsigned short*)alloc((size_t)ROWS * DIMN * 2);
    unsigned short* attn = (unsigned short*)alloc((size_t)ROWS * DIMN * 2);
    float*          part = (float*)alloc((size_t)32 * 8 * HD * HD * 4);
    unsigned short* M2   = (unsigned short*)alloc((size_t)32 * HD * HD * 2);

    // converts
    cvt_kernel<<<(ROWS * DIMN / 4 + 255) / 256, 256, 0, stream>>>(x, Xb, ROWS * DIMN);
    cvt_kernel<<<(DIMN * DIMN / 4 + 255) / 256, 256, 0, stream>>>(wq, Wq, DIMN * DIMN);
    cvt_kernel<<<(DIMN * DIMN / 4 + 255) / 256, 256, 0, stream>>>(wk, Wk, DIMN * DIMN);
    cvt_kernel<<<(DIMN * DIMN / 4 + 255) / 256, 256, 0, stream>>>(wv, Wv, DIMN * DIMN);
    cvt_kernel<<<(DIMN * DIMN / 4 + 255) / 256, 256, 0, stream>>>(wo, Wo, DIMN * DIMN);

    // Q,K,V projections
    dim3 g(DIMN / 128, ROWS / 128);
    gemm_bt<1, 1><<<g, 256, 0, stream>>>(Xb, Wq, bq, Qb, DIMN, DIMN, DIMN, DIMN);
    gemm_bt<1, 1><<<g, 256, 0, stream>>>(Xb, Wk, bk, Kb, DIMN, DIMN, DIMN, DIMN);
    gemm_bt<1, 1><<<g, 256, 0, stream>>>(Xb, Wv, bv, Vb, DIMN, DIMN, DIMN, DIMN);

    // RoPE on Q and K
    rope_kernel<<<ROWS * 1024 / 256, 256, 0, stream>>>(Qb, Kb, fcos, fsin);

    // K^T V (reassociated attention: no softmax in reference!)
    ktv_kernel<<<dim3(8, 32), 256, 0, stream>>>(Kb, Vb, part);
    ktv_reduce<<<(32 * 16384) / 256, 256, 0, stream>>>(part, M2);

    // attn = Q @ M2^T per head
    qm_gemm<<<dim3(32, 16), 256, 0, stream>>>(Qb, M2, attn);

    // out = attn @ Wo^T + bo  (f32 output)
    gemm_bt<0, 1><<<g, 256, 0, stream>>>(attn, Wo, bo, out, DIMN, DIMN, DIMN, DIMN);
}

// Round 2
// 248.683 us; speedup vs baseline: 1.0725x; 1.0725x over previous
//
#include <hip/hip_runtime.h>
#include <hip/hip_bf16.h>

#define DIMN 2048
#define NQKV 6144
#define NH 16
#define HD 128
#define BSZ 2
#define SEQ 2048
#define ROWS (BSZ*SEQ)   // 4096

typedef short short8 __attribute__((ext_vector_type(8)));
typedef float f32x4 __attribute__((ext_vector_type(4)));

__device__ __forceinline__ unsigned short f2bf(float f) {
    __hip_bfloat16 h = __float2bfloat16(f);
    unsigned short u; __builtin_memcpy(&u, &h, 2); return u;
}
__device__ __forceinline__ float bf2f(unsigned short u) {
    unsigned x = ((unsigned)u) << 16; float f; __builtin_memcpy(&f, &x, 4); return f;
}

__device__ __forceinline__ void gld_lds16(const void* g, void* l) {
    __builtin_amdgcn_global_load_lds(
        (const __attribute__((address_space(1))) void*)g,
        (__attribute__((address_space(3))) void*)l, 16, 0, 0);
}

// ---------------- f32 -> bf16 convert ----------------
__global__ void cvt_kernel(const float* __restrict__ in, unsigned short* __restrict__ out, int n) {
    int i = (blockIdx.x * 256 + threadIdx.x) * 4;
    if (i >= n) return;
    float4 v = *(const float4*)(in + i);
    ushort4 o;
    o.x = f2bf(v.x); o.y = f2bf(v.y); o.z = f2bf(v.z); o.w = f2bf(v.w);
    *(ushort4*)(out + i) = o;
}

// ================= deep-pipelined GEMM: C[m][n] = sum_k A[m][k]*B[n][k] =================
// BM=128, BN=256, BK=32, 512 threads (8 waves 2Mx4N, per-wave 64x64), 4 LDS k-tile buffers.
// Counted vmcnt(6) keeps 2 k-tiles of global_load_lds in flight across barriers.
// LDS XOR-swizzle: 16B-column q' = q ^ ((row>>1)&3); source pre-swizzled so gld_lds stays linear.
// MODE 0: bf16 out, per-region QKV bias + fused RoPE on Q,K columns. MODE 1: f32 out + bias.
template<int MODE>
__global__ __launch_bounds__(512, 2) void gemm8p(
    const unsigned short* __restrict__ A, int lda,
    const unsigned short* __restrict__ B, int ldb,
    const float* __restrict__ b0, const float* __restrict__ b1, const float* __restrict__ b2,
    const float* __restrict__ fcos, const float* __restrict__ fsin,
    void* __restrict__ C, int ldc, int K)
{
    __shared__ __align__(16) unsigned short As[4 * 128 * 32];  // 32 KiB
    __shared__ __align__(16) unsigned short Bs[4 * 256 * 32];  // 64 KiB

    const int t  = threadIdx.x;
    const int l  = t & 63;
    const int w  = t >> 6;
    const int wr = w >> 2;          // 0..1
    const int wc = w & 3;           // 0..3
    const int fr = l & 15, fq = l >> 4;

    const int n0 = blockIdx.x * 256;
    const int m0 = blockIdx.y * 128;

    // ---- staging source (pre-swizzled global column so linear LDS dest matches swizzled reads)
    const int sr  = t >> 2;                    // 0..127
    const int sq  = (t & 3) ^ ((sr >> 1) & 3); // swizzled 16B-column index
    const unsigned short* aSrc  = A + (size_t)(m0 + sr) * lda + sq * 8;
    const unsigned short* bSrc0 = B + (size_t)(n0 + sr) * ldb + sq * 8;
    const unsigned short* bSrc1 = B + (size_t)(n0 + 128 + sr) * ldb + sq * 8;

    auto stage = [&](int kt) {
        const int buf = kt & 3;
        gld_lds16(aSrc  + kt * 32, &As[buf * 4096 + t * 8]);
        gld_lds16(bSrc0 + kt * 32, &Bs[buf * 8192 + t * 8]);
        gld_lds16(bSrc1 + kt * 32, &Bs[buf * 8192 + 4096 + t * 8]);
    };

    // ---- swizzled ds_read bases (col swizzle is mi/ni-independent: (row>>1)&3 == (fr>>1)&3)
    const int colOff = (fq ^ ((fr >> 1) & 3)) * 8;
    const int aBase  = (wr * 64 + fr) * 32 + colOff;   // + mi*512
    const int bBase  = (wc * 64 + fr) * 32 + colOff;   // + ni*512

    f32x4 acc[4][4] = {};

    const int ktT = K / 32;   // 64 for K=2048; must be %4==0 and >= 8

    // prologue: 3 k-tiles in flight, wait for the first
    stage(0); stage(1); stage(2);
    asm volatile("s_waitcnt vmcnt(6)");
    __builtin_amdgcn_s_barrier();
    __builtin_amdgcn_sched_barrier(0);

#define PHASE(KT, BUF, VMSTR, STG, TRAIL)                                           \
  do {                                                                              \
    short8 a_[4], b_[4];                                                            \
    _Pragma("unroll")                                                               \
    for (int mi = 0; mi < 4; ++mi)                                                  \
      a_[mi] = *(const short8*)&As[(BUF) * 4096 + aBase + mi * 512];                \
    _Pragma("unroll")                                                               \
    for (int ni = 0; ni < 4; ++ni)                                                  \
      b_[ni] = *(const short8*)&Bs[(BUF) * 8192 + bBase + ni * 512];                \
    if (STG) stage((KT) + 3);                                                       \
    __builtin_amdgcn_s_barrier();                                                   \
    asm volatile("s_waitcnt lgkmcnt(0)");                                           \
    __builtin_amdgcn_sched_barrier(0);                                              \
    __builtin_amdgcn_s_setprio(1);                                                  \
    _Pragma("unroll")                                                               \
    for (int mi = 0; mi < 4; ++mi)                                                  \
      _Pragma("unroll")                                                             \
      for (int ni = 0; ni < 4; ++ni)                                                \
        acc[mi][ni] = __builtin_amdgcn_mfma_f32_16x16x32_bf16(a_[mi], b_[ni],       \
                                                              acc[mi][ni], 0, 0, 0);\
    __builtin_amdgcn_s_setprio(0);                                                  \
    if (TRAIL) {                                                                    \
      asm volatile("s_waitcnt " VMSTR);                                             \
      __builtin_amdgcn_s_barrier();                                                 \
      __builtin_amdgcn_sched_barrier(0);                                            \
    }                                                                               \
  } while (0)

    int kt = 0;
    for (; kt + 4 < ktT; kt += 4) {
        PHASE(kt + 0, 0, "vmcnt(6)", 1, 1);
        PHASE(kt + 1, 1, "vmcnt(6)", 1, 1);
        PHASE(kt + 2, 2, "vmcnt(6)", 1, 1);
        PHASE(kt + 3, 3, "vmcnt(6)", 1, 1);
    }
    // kt == ktT-4 here (ktT % 4 == 0)
    PHASE(ktT - 4, 0, "vmcnt(6)", 1, 1);
    PHASE(ktT - 3, 1, "vmcnt(3)", 0, 1);
    PHASE(ktT - 2, 2, "vmcnt(0)", 0, 1);
    PHASE(ktT - 1, 3, "vmcnt(0)", 0, 0);
#undef PHASE

    // ---- epilogue: bias (+ RoPE for MODE 0 on cols < 4096), store
    #pragma unroll
    for (int mi = 0; mi < 4; ++mi) {
        #pragma unroll
        for (int ni = 0; ni < 4; ++ni) {
            #pragma unroll
            for (int j = 0; j < 4; ++j) {
                const int r  = wr * 64 + mi * 16 + fq * 4 + j;
                const int c  = wc * 64 + ni * 16 + fr;
                const int cg = n0 + c;
                float v = acc[mi][ni][j];
                if (MODE == 0) {
                    v += (cg < 2048) ? b0[cg] : ((cg < 4096) ? b1[cg - 2048] : b2[cg - 4096]);
                    if (cg < 4096) {  // block-uniform: RoPE on Q and K
                        const int s = (m0 + r) & (SEQ - 1);
                        const int i = (cg >> 1) & 63;
                        const float cs = fcos[s * 64 + i];
                        const float sn = fsin[s * 64 + i];
                        const float p  = __shfl_xor(v, 1);
                        v = (fr & 1) ? (p * sn + v * cs) : (v * cs - p * sn);
                    }
                    ((unsigned short*)C)[(size_t)(m0 + r) * ldc + cg] = f2bf(v);
                } else {
                    v += b0[cg];
                    ((float*)C)[(size_t)(m0 + r) * ldc + cg] = v;
                }
            }
        }
    }
}

// ---------------- old 128x128 GEMM core (kept for the tiny per-head Q@M2 GEMM) ----------------
template<int OUT_BF16, int HAS_BIAS>
__device__ __forceinline__ void gemm_tile_core(
    const unsigned short* __restrict__ A, int lda,
    const unsigned short* __restrict__ B, int ldb,
    const float* __restrict__ bias,
    void* __restrict__ Cptr, int ldc, int K)
{
    __shared__ __align__(16) unsigned short As[128 * 64];
    __shared__ __align__(16) unsigned short Bs[128 * 64];

    const int t  = threadIdx.x;
    const int l  = t & 63;
    const int w  = t >> 6;
    const int wr = w >> 1, wc = w & 1;
    const int fr = l & 15, fq = l >> 4;

    f32x4 acc[4][4] = {};

    const int srow = t >> 3;
    const int scol = (t & 7) * 8;

    for (int k0 = 0; k0 < K; k0 += 64) {
        __syncthreads();
        #pragma unroll
        for (int r = 0; r < 4; ++r) {
            gld_lds16(A + (size_t)(r * 32 + srow) * lda + k0 + scol, &As[(r * 32 + srow) * 64 + scol]);
            gld_lds16(B + (size_t)(r * 32 + srow) * ldb + k0 + scol, &Bs[(r * 32 + srow) * 64 + scol]);
        }
        __syncthreads();
        #pragma unroll
        for (int kk = 0; kk < 2; ++kk) {
            short8 a[4], b[4];
            #pragma unroll
            for (int mi = 0; mi < 4; ++mi)
                a[mi] = *(const short8*)&As[(wr * 64 + mi * 16 + fr) * 64 + kk * 32 + fq * 8];
            #pragma unroll
            for (int ni = 0; ni < 4; ++ni)
                b[ni] = *(const short8*)&Bs[(wc * 64 + ni * 16 + fr) * 64 + kk * 32 + fq * 8];
            #pragma unroll
            for (int mi = 0; mi < 4; ++mi)
                #pragma unroll
                for (int ni = 0; ni < 4; ++ni)
                    acc[mi][ni] = __builtin_amdgcn_mfma_f32_16x16x32_bf16(a[mi], b[ni], acc[mi][ni], 0, 0, 0);
        }
    }

    #pragma unroll
    for (int mi = 0; mi < 4; ++mi) {
        #pragma unroll
        for (int ni = 0; ni < 4; ++ni) {
            #pragma unroll
            for (int j = 0; j < 4; ++j) {
                int rr = wr * 64 + mi * 16 + fq * 4 + j;
                int cc = wc * 64 + ni * 16 + fr;
                float v = acc[mi][ni][j];
                if (HAS_BIAS) v += bias[cc];
                if (OUT_BF16) ((unsigned short*)Cptr)[(size_t)rr * ldc + cc] = f2bf(v);
                else          ((float*)Cptr)[(size_t)rr * ldc + cc] = v;
            }
        }
    }
}

// ---------------- per-head Q @ M2^T ----------------
__global__ __launch_bounds__(256) void qm_gemm(
    const unsigned short* __restrict__ QKV, const unsigned short* __restrict__ M2,
    unsigned short* __restrict__ attn)
{
    const int mt = blockIdx.x;  // 0..31
    const int h  = blockIdx.y;  // 0..15
    const int b  = mt >> 4;
    const unsigned short* A = QKV + (size_t)(mt * 128) * NQKV + h * HD;
    const unsigned short* B = M2 + (size_t)(b * NH + h) * HD * HD;
    unsigned short* Cb = attn + (size_t)(mt * 128) * DIMN + h * HD;
    gemm_tile_core<1, 0>(A, NQKV, B, HD, nullptr, Cb, DIMN, HD);
}

// ---------------- K^T V partials ----------------
__global__ __launch_bounds__(256) void ktv_kernel(
    const unsigned short* __restrict__ QKV, float* __restrict__ part)
{
    const int ks = blockIdx.x;  // 0..7
    const int bh = blockIdx.y;  // 0..31
    const int b = bh >> 4, h = bh & 15;
    const unsigned short* Kbase = QKV + (size_t)(b * SEQ + ks * 256) * NQKV + 2048 + h * HD;
    const unsigned short* Vbase = QKV + (size_t)(b * SEQ + ks * 256) * NQKV + 4096 + h * HD;

    __shared__ __align__(16) unsigned short Ks_[64 * 128];
    __shared__ __align__(16) unsigned short Vs_[64 * 128];

    const int t  = threadIdx.x;
    const int l  = t & 63;
    const int w  = t >> 6;
    const int wr = w >> 1, wc = w & 1;
    const int fr = l & 15, fq = l >> 4;

    f32x4 acc[4][4] = {};

    const int srow = t >> 4;
    const int scol = (t & 15) * 8;

    for (int sc = 0; sc < 4; ++sc) {
        __syncthreads();
        #pragma unroll
        for (int r = 0; r < 4; ++r) {
            gld_lds16(Kbase + (size_t)(sc * 64 + r * 16 + srow) * NQKV + scol, &Ks_[(r * 16 + srow) * 128 + scol]);
            gld_lds16(Vbase + (size_t)(sc * 64 + r * 16 + srow) * NQKV + scol, &Vs_[(r * 16 + srow) * 128 + scol]);
        }
        __syncthreads();
        #pragma unroll
        for (int kk = 0; kk < 2; ++kk) {
            short8 a[4], bb[4];
            #pragma unroll
            for (int mi = 0; mi < 4; ++mi)
                #pragma unroll
                for (int i = 0; i < 8; ++i)
                    a[mi][i] = (short)Vs_[(kk * 32 + fq * 8 + i) * 128 + wr * 64 + mi * 16 + fr];
            #pragma unroll
            for (int ni = 0; ni < 4; ++ni)
                #pragma unroll
                for (int i = 0; i < 8; ++i)
                    bb[ni][i] = (short)Ks_[(kk * 32 + fq * 8 + i) * 128 + wc * 64 + ni * 16 + fr];
            #pragma unroll
            for (int mi = 0; mi < 4; ++mi)
                #pragma unroll
                for (int ni = 0; ni < 4; ++ni)
                    acc[mi][ni] = __builtin_amdgcn_mfma_f32_16x16x32_bf16(a[mi], bb[ni], acc[mi][ni], 0, 0, 0);
        }
    }

    float* base = part + ((size_t)bh * 8 + ks) * 16384;
    #pragma unroll
    for (int mi = 0; mi < 4; ++mi)
        #pragma unroll
        for (int ni = 0; ni < 4; ++ni)
            #pragma unroll
            for (int j = 0; j < 4; ++j)
                base[(wr * 64 + mi * 16 + fq * 4 + j) * 128 + wc * 64 + ni * 16 + fr] = acc[mi][ni][j];
}

// ---------------- reduce partials, scale, -> bf16 M2 ----------------
__global__ void ktv_reduce(const float* __restrict__ part, unsigned short* __restrict__ M2) {
    int idx = blockIdx.x * 256 + threadIdx.x;
    int bh = idx >> 14, rem = idx & 16383;
    const float* p = part + ((size_t)bh * 8) * 16384 + rem;
    float s = 0.f;
    #pragma unroll
    for (int k = 0; k < 8; ++k) s += p[(size_t)k * 16384];
    M2[idx] = f2bf(s * 0.08838834764831845f);  // 1/sqrt(128)
}

extern "C" void kernel_launch(void* const* d_in, const int* in_sizes, int n_in,
                              void* d_out, int out_size, void* d_ws, size_t ws_size,
                              hipStream_t stream) {
    const float* x    = (const float*)d_in[0];
    const float* fcos = (const float*)d_in[1];
    const float* fsin = (const float*)d_in[2];
    const float* wq   = (const float*)d_in[3];
    const float* bq   = (const float*)d_in[4];
    const float* wk   = (const float*)d_in[5];
    const float* bk   = (const float*)d_in[6];
    const float* wv   = (const float*)d_in[7];
    const float* bv   = (const float*)d_in[8];
    const float* wo   = (const float*)d_in[9];
    const float* bo   = (const float*)d_in[10];
    float* out = (float*)d_out;

    char* ws = (char*)d_ws;
    size_t off = 0;
    auto alloc = [&](size_t bytes) { char* p = ws + off; off += (bytes + 255) & ~(size_t)255; return p; };

    unsigned short* Xb   = (unsigned short*)alloc((size_t)ROWS * DIMN * 2);
    unsigned short* Wcat = (unsigned short*)alloc((size_t)NQKV * DIMN * 2);
    unsigned short* Wo   = (unsigned short*)alloc((size_t)DIMN * DIMN * 2);
    unsigned short* QKV  = (unsigned short*)alloc((size_t)ROWS * NQKV * 2);
    unsigned short* attn = (unsigned short*)alloc((size_t)ROWS * DIMN * 2);
    float*          part = (float*)alloc((size_t)32 * 8 * HD * HD * 4);
    unsigned short* M2   = (unsigned short*)alloc((size_t)32 * HD * HD * 2);

    // converts (weights concatenated into Wcat rows: [Wq; Wk; Wv])
    cvt_kernel<<<(ROWS * DIMN / 4 + 255) / 256, 256, 0, stream>>>(x, Xb, ROWS * DIMN);
    cvt_kernel<<<(DIMN * DIMN / 4 + 255) / 256, 256, 0, stream>>>(wq, Wcat, DIMN * DIMN);
    cvt_kernel<<<(DIMN * DIMN / 4 + 255) / 256, 256, 0, stream>>>(wk, Wcat + (size_t)DIMN * DIMN, DIMN * DIMN);
    cvt_kernel<<<(DIMN * DIMN / 4 + 255) / 256, 256, 0, stream>>>(wv, Wcat + (size_t)2 * DIMN * DIMN, DIMN * DIMN);
    cvt_kernel<<<(DIMN * DIMN / 4 + 255) / 256, 256, 0, stream>>>(wo, Wo, DIMN * DIMN);

    // fused QKV projection + bias + RoPE  (M=4096, N=6144, K=2048)
    gemm8p<0><<<dim3(NQKV / 256, ROWS / 128), 512, 0, stream>>>(
        Xb, DIMN, Wcat, DIMN, bq, bk, bv, fcos, fsin, QKV, NQKV, DIMN);

    // reassociated attention (no softmax): M2 = (K^T V)/sqrt(d) per (b,h)
    ktv_kernel<<<dim3(8, 32), 256, 0, stream>>>(QKV, part);
    ktv_reduce<<<(32 * 16384) / 256, 256, 0, stream>>>(part, M2);

    // attn = Q @ M2^T per head
    qm_gemm<<<dim3(32, 16), 256, 0, stream>>>(QKV, M2, attn);

    // out = attn @ Wo^T + bo  (M=4096, N=2048, K=2048, f32 out)
    gemm8p<1><<<dim3(DIMN / 256, ROWS / 128), 512, 0, stream>>>(
        attn, DIMN, Wo, DIMN, bo, nullptr, nullptr, nullptr, nullptr, out, DIMN, DIMN);
}

// Round 3
// 245.712 us; speedup vs baseline: 1.0854x; 1.0121x over previous
//
#include <hip/hip_runtime.h>
#include <hip/hip_bf16.h>

#define DIMN 2048
#define NQKV 6144
#define NH 16
#define HD 128
#define BSZ 2
#define SEQ 2048
#define ROWS (BSZ*SEQ)   // 4096

typedef short short8 __attribute__((ext_vector_type(8)));
typedef float f32x4 __attribute__((ext_vector_type(4)));

__device__ __forceinline__ unsigned short f2bf(float f) {
    __hip_bfloat16 h = __float2bfloat16(f);
    unsigned short u; __builtin_memcpy(&u, &h, 2); return u;
}
__device__ __forceinline__ float bf2f(unsigned short u) {
    unsigned x = ((unsigned)u) << 16; float f; __builtin_memcpy(&f, &x, 4); return f;
}

__device__ __forceinline__ void gld_lds16(const void* g, void* l) {
    __builtin_amdgcn_global_load_lds(
        (const __attribute__((address_space(1))) void*)g,
        (__attribute__((address_space(3))) void*)l, 16, 0, 0);
}

// ---------------- f32 -> bf16 convert ----------------
__global__ void cvt_kernel(const float* __restrict__ in, unsigned short* __restrict__ out, int n) {
    int i = (blockIdx.x * 256 + threadIdx.x) * 4;
    if (i >= n) return;
    float4 v = *(const float4*)(in + i);
    ushort4 o;
    o.x = f2bf(v.x); o.y = f2bf(v.y); o.z = f2bf(v.z); o.w = f2bf(v.w);
    *(ushort4*)(out + i) = o;
}

// ================= pipelined GEMM: C[m][n] = sum_k A[m][k]*B[n][k] =================
// BM=128, BN=256, BK=64, 512 threads (8 waves 2Mx4N, per-wave 64x64).
// 3-buffer LDS ring (144 KiB): phase kt computes buf kt%3, stages kt+2 -> 2-deep prefetch.
// Trailing s_waitcnt vmcnt(6) retires the oldest K-tile (6 loads/tile, 12 outstanding).
// Bare asm s_barrier (no counter drain) + sched_barrier fences.
// LDS swizzle: 16B-col' = col ^ (row&7)  (row stride 128B); source pre-swizzled so the
// global_load_lds destination stays linear (guide rule 21).
// MODE 0: bf16 out, QKV region bias + fused RoPE. MODE 1: f32 out + bias.
template<int MODE>
__global__ __launch_bounds__(512, 2) void gemm_p3(
    const unsigned short* __restrict__ A, int lda,
    const unsigned short* __restrict__ B, int ldb,
    const float* __restrict__ b0, const float* __restrict__ b1, const float* __restrict__ b2,
    const float* __restrict__ fcos, const float* __restrict__ fsin,
    void* __restrict__ C, int ldc, int K)
{
    __shared__ __align__(16) unsigned short As[3 * 128 * 64];  // 48 KiB
    __shared__ __align__(16) unsigned short Bs[3 * 256 * 64];  // 96 KiB

    const int t  = threadIdx.x;
    const int l  = t & 63;
    const int w  = t >> 6;
    const int wr = w >> 2;          // 0..1
    const int wc = w & 3;           // 0..3
    const int fr = l & 15, fq = l >> 4;

    const int n0 = blockIdx.x * 256;
    const int m0 = blockIdx.y * 128;

    // ---- staging: thread covers row sr (+64j), 16B-col (t&7), source col pre-swizzled
    const int sr = t >> 3;                          // 0..63
    const int sc = ((t & 7) ^ (sr & 7)) * 8;        // swizzled source element col
    const unsigned short* aSrc = A + (size_t)(m0 + sr) * lda + sc;
    const unsigned short* bSrc = B + (size_t)(n0 + sr) * ldb + sc;

    auto stage = [&](int kt, int buf) {
        const unsigned short* a = aSrc + kt * 64;
        const unsigned short* b = bSrc + kt * 64;
        gld_lds16(a,                      &As[buf * 8192 + t * 8]);
        gld_lds16(a + (size_t)64 * lda,   &As[buf * 8192 + 4096 + t * 8]);
        gld_lds16(b,                      &Bs[buf * 16384 + t * 8]);
        gld_lds16(b + (size_t)64 * ldb,   &Bs[buf * 16384 + 4096 + t * 8]);
        gld_lds16(b + (size_t)128 * ldb,  &Bs[buf * 16384 + 8192 + t * 8]);
        gld_lds16(b + (size_t)192 * ldb,  &Bs[buf * 16384 + 12288 + t * 8]);
    };

    // ---- swizzled ds_read offsets (row&7 == fr&7 since wr*64, wc*64, mi*16 are %8==0)
    const int kOff0 = ((0 + fq) ^ (fr & 7)) * 8;
    const int kOff1 = ((4 + fq) ^ (fr & 7)) * 8;
    const int aBase = (wr * 64 + fr) * 64;   // + mi*1024
    const int bBase = (wc * 64 + fr) * 64;   // + ni*1024

    f32x4 acc[4][4] = {};

    const int ktT = K / 64;   // 32 for K=2048 (ktT % 3 == 2 assumed)

    // prologue: 2 K-tiles in flight, wait for tile 0 (12 outstanding -> 6)
    stage(0, 0); stage(1, 1);
    asm volatile("s_waitcnt vmcnt(6)");
    __builtin_amdgcn_sched_barrier(0);
    asm volatile("s_barrier");
    __builtin_amdgcn_sched_barrier(0);

#define PHASE(KT, BUF, SBUF, STG, VMSTR, TRAIL)                                      \
  do {                                                                               \
    short8 a_[4][2], b_[4][2];                                                       \
    _Pragma("unroll")                                                                \
    for (int mi = 0; mi < 4; ++mi) {                                                 \
      a_[mi][0] = *(const short8*)&As[(BUF) * 8192 + aBase + mi * 1024 + kOff0];     \
      a_[mi][1] = *(const short8*)&As[(BUF) * 8192 + aBase + mi * 1024 + kOff1];     \
    }                                                                                \
    _Pragma("unroll")                                                                \
    for (int ni = 0; ni < 4; ++ni) {                                                 \
      b_[ni][0] = *(const short8*)&Bs[(BUF) * 16384 + bBase + ni * 1024 + kOff0];    \
      b_[ni][1] = *(const short8*)&Bs[(BUF) * 16384 + bBase + ni * 1024 + kOff1];    \
    }                                                                                \
    if (STG) stage((KT) + 2, (SBUF));                                                \
    __builtin_amdgcn_sched_barrier(0);                                               \
    asm volatile("s_barrier");                                                       \
    asm volatile("s_waitcnt lgkmcnt(0)");                                            \
    __builtin_amdgcn_sched_barrier(0);                                               \
    __builtin_amdgcn_s_setprio(1);                                                   \
    _Pragma("unroll")                                                                \
    for (int kk = 0; kk < 2; ++kk)                                                   \
      _Pragma("unroll")                                                              \
      for (int mi = 0; mi < 4; ++mi)                                                 \
        _Pragma("unroll")                                                            \
        for (int ni = 0; ni < 4; ++ni)                                               \
          acc[mi][ni] = __builtin_amdgcn_mfma_f32_16x16x32_bf16(a_[mi][kk],          \
                                         b_[ni][kk], acc[mi][ni], 0, 0, 0);          \
    __builtin_amdgcn_s_setprio(0);                                                   \
    __builtin_amdgcn_sched_barrier(0);                                               \
    if (TRAIL) {                                                                     \
      asm volatile("s_waitcnt " VMSTR);                                              \
      __builtin_amdgcn_sched_barrier(0);                                             \
      asm volatile("s_barrier");                                                     \
      __builtin_amdgcn_sched_barrier(0);                                             \
    }                                                                                \
  } while (0)

    int kt = 0;
    for (; kt + 5 < ktT; kt += 3) {
        PHASE(kt + 0, 0, 2, 1, "vmcnt(6)", 1);
        PHASE(kt + 1, 1, 0, 1, "vmcnt(6)", 1);
        PHASE(kt + 2, 2, 1, 1, "vmcnt(6)", 1);
    }
    // remainder: ktT % 3 == 2 -> 5 phases, bufs 0,1,2,0,1
    PHASE(ktT - 5, 0, 2, 1, "vmcnt(6)", 1);
    PHASE(ktT - 4, 1, 0, 1, "vmcnt(6)", 1);
    PHASE(ktT - 3, 2, 1, 1, "vmcnt(6)", 1);
    PHASE(ktT - 2, 0, 0, 0, "vmcnt(0)", 1);
    PHASE(ktT - 1, 1, 0, 0, "vmcnt(0)", 0);
#undef PHASE

    // ---- epilogue: bias (+ RoPE for MODE 0 on cols < 4096), store
    #pragma unroll
    for (int mi = 0; mi < 4; ++mi) {
        #pragma unroll
        for (int ni = 0; ni < 4; ++ni) {
            #pragma unroll
            for (int j = 0; j < 4; ++j) {
                const int r  = wr * 64 + mi * 16 + fq * 4 + j;
                const int c  = wc * 64 + ni * 16 + fr;
                const int cg = n0 + c;
                float v = acc[mi][ni][j];
                if (MODE == 0) {
                    v += (cg < 2048) ? b0[cg] : ((cg < 4096) ? b1[cg - 2048] : b2[cg - 4096]);
                    if (cg < 4096) {  // block-uniform: RoPE on Q and K
                        const int s = (m0 + r) & (SEQ - 1);
                        const int i = (cg >> 1) & 63;
                        const float cs = fcos[s * 64 + i];
                        const float sn = fsin[s * 64 + i];
                        const float p  = __shfl_xor(v, 1);
                        v = (fr & 1) ? (p * sn + v * cs) : (v * cs - p * sn);
                    }
                    ((unsigned short*)C)[(size_t)(m0 + r) * ldc + cg] = f2bf(v);
                } else {
                    v += b0[cg];
                    ((float*)C)[(size_t)(m0 + r) * ldc + cg] = v;
                }
            }
        }
    }
}

// ---------------- old 128x128 GEMM core (tiny per-head Q@M2 GEMM) ----------------
template<int OUT_BF16, int HAS_BIAS>
__device__ __forceinline__ void gemm_tile_core(
    const unsigned short* __restrict__ A, int lda,
    const unsigned short* __restrict__ B, int ldb,
    const float* __restrict__ bias,
    void* __restrict__ Cptr, int ldc, int K)
{
    __shared__ __align__(16) unsigned short As[128 * 64];
    __shared__ __align__(16) unsigned short Bs[128 * 64];

    const int t  = threadIdx.x;
    const int l  = t & 63;
    const int w  = t >> 6;
    const int wr = w >> 1, wc = w & 1;
    const int fr = l & 15, fq = l >> 4;

    f32x4 acc[4][4] = {};

    const int srow = t >> 3;
    const int scol = (t & 7) * 8;

    for (int k0 = 0; k0 < K; k0 += 64) {
        __syncthreads();
        #pragma unroll
        for (int r = 0; r < 4; ++r) {
            gld_lds16(A + (size_t)(r * 32 + srow) * lda + k0 + scol, &As[(r * 32 + srow) * 64 + scol]);
            gld_lds16(B + (size_t)(r * 32 + srow) * ldb + k0 + scol, &Bs[(r * 32 + srow) * 64 + scol]);
        }
        __syncthreads();
        #pragma unroll
        for (int kk = 0; kk < 2; ++kk) {
            short8 a[4], b[4];
            #pragma unroll
            for (int mi = 0; mi < 4; ++mi)
                a[mi] = *(const short8*)&As[(wr * 64 + mi * 16 + fr) * 64 + kk * 32 + fq * 8];
            #pragma unroll
            for (int ni = 0; ni < 4; ++ni)
                b[ni] = *(const short8*)&Bs[(wc * 64 + ni * 16 + fr) * 64 + kk * 32 + fq * 8];
            #pragma unroll
            for (int mi = 0; mi < 4; ++mi)
                #pragma unroll
                for (int ni = 0; ni < 4; ++ni)
                    acc[mi][ni] = __builtin_amdgcn_mfma_f32_16x16x32_bf16(a[mi], b[ni], acc[mi][ni], 0, 0, 0);
        }
    }

    #pragma unroll
    for (int mi = 0; mi < 4; ++mi) {
        #pragma unroll
        for (int ni = 0; ni < 4; ++ni) {
            #pragma unroll
            for (int j = 0; j < 4; ++j) {
                int rr = wr * 64 + mi * 16 + fq * 4 + j;
                int cc = wc * 64 + ni * 16 + fr;
                float v = acc[mi][ni][j];
                if (HAS_BIAS) v += bias[cc];
                if (OUT_BF16) ((unsigned short*)Cptr)[(size_t)rr * ldc + cc] = f2bf(v);
                else          ((float*)Cptr)[(size_t)rr * ldc + cc] = v;
            }
        }
    }
}

// ---------------- per-head Q @ M2^T ----------------
__global__ __launch_bounds__(256) void qm_gemm(
    const unsigned short* __restrict__ QKV, const unsigned short* __restrict__ M2,
    unsigned short* __restrict__ attn)
{
    const int mt = blockIdx.x;  // 0..31
    const int h  = blockIdx.y;  // 0..15
    const int b  = mt >> 4;
    const unsigned short* A = QKV + (size_t)(mt * 128) * NQKV + h * HD;
    const unsigned short* B = M2 + (size_t)(b * NH + h) * HD * HD;
    unsigned short* Cb = attn + (size_t)(mt * 128) * DIMN + h * HD;
    gemm_tile_core<1, 0>(A, NQKV, B, HD, nullptr, Cb, DIMN, HD);
}

// ---------------- K^T V partials ----------------
__global__ __launch_bounds__(256) void ktv_kernel(
    const unsigned short* __restrict__ QKV, float* __restrict__ part)
{
    const int ks = blockIdx.x;  // 0..7
    const int bh = blockIdx.y;  // 0..31
    const int b = bh >> 4, h = bh & 15;
    const unsigned short* Kbase = QKV + (size_t)(b * SEQ + ks * 256) * NQKV + 2048 + h * HD;
    const unsigned short* Vbase = QKV + (size_t)(b * SEQ + ks * 256) * NQKV + 4096 + h * HD;

    __shared__ __align__(16) unsigned short Ks_[64 * 128];
    __shared__ __align__(16) unsigned short Vs_[64 * 128];

    const int t  = threadIdx.x;
    const int l  = t & 63;
    const int w  = t >> 6;
    const int wr = w >> 1, wc = w & 1;
    const int fr = l & 15, fq = l >> 4;

    f32x4 acc[4][4] = {};

    const int srow = t >> 4;
    const int scol = (t & 15) * 8;

    for (int sc = 0; sc < 4; ++sc) {
        __syncthreads();
        #pragma unroll
        for (int r = 0; r < 4; ++r) {
            gld_lds16(Kbase + (size_t)(sc * 64 + r * 16 + srow) * NQKV + scol, &Ks_[(r * 16 + srow) * 128 + scol]);
            gld_lds16(Vbase + (size_t)(sc * 64 + r * 16 + srow) * NQKV + scol, &Vs_[(r * 16 + srow) * 128 + scol]);
        }
        __syncthreads();
        #pragma unroll
        for (int kk = 0; kk < 2; ++kk) {
            short8 a[4], bb[4];
            #pragma unroll
            for (int mi = 0; mi < 4; ++mi)
                #pragma unroll
                for (int i = 0; i < 8; ++i)
                    a[mi][i] = (short)Vs_[(kk * 32 + fq * 8 + i) * 128 + wr * 64 + mi * 16 + fr];
            #pragma unroll
            for (int ni = 0; ni < 4; ++ni)
                #pragma unroll
                for (int i = 0; i < 8; ++i)
                    bb[ni][i] = (short)Ks_[(kk * 32 + fq * 8 + i) * 128 + wc * 64 + ni * 16 + fr];
            #pragma unroll
            for (int mi = 0; mi < 4; ++mi)
                #pragma unroll
                for (int ni = 0; ni < 4; ++ni)
                    acc[mi][ni] = __builtin_amdgcn_mfma_f32_16x16x32_bf16(a[mi], bb[ni], acc[mi][ni], 0, 0, 0);
        }
    }

    float* base = part + ((size_t)bh * 8 + ks) * 16384;
    #pragma unroll
    for (int mi = 0; mi < 4; ++mi)
        #pragma unroll
        for (int ni = 0; ni < 4; ++ni)
            #pragma unroll
            for (int j = 0; j < 4; ++j)
                base[(wr * 64 + mi * 16 + fq * 4 + j) * 128 + wc * 64 + ni * 16 + fr] = acc[mi][ni][j];
}

// ---------------- reduce partials, scale, -> bf16 M2 ----------------
__global__ void ktv_reduce(const float* __restrict__ part, unsigned short* __restrict__ M2) {
    int idx = blockIdx.x * 256 + threadIdx.x;
    int bh = idx >> 14, rem = idx & 16383;
    const float* p = part + ((size_t)bh * 8) * 16384 + rem;
    float s = 0.f;
    #pragma unroll
    for (int k = 0; k < 8; ++k) s += p[(size_t)k * 16384];
    M2[idx] = f2bf(s * 0.08838834764831845f);  // 1/sqrt(128)
}

extern "C" void kernel_launch(void* const* d_in, const int* in_sizes, int n_in,
                              void* d_out, int out_size, void* d_ws, size_t ws_size,
                              hipStream_t stream) {
    const float* x    = (const float*)d_in[0];
    const float* fcos = (const float*)d_in[1];
    const float* fsin = (const float*)d_in[2];
    const float* wq   = (const float*)d_in[3];
    const float* bq   = (const float*)d_in[4];
    const float* wk   = (const float*)d_in[5];
    const float* bk   = (const float*)d_in[6];
    const float* wv   = (const float*)d_in[7];
    const float* bv   = (const float*)d_in[8];
    const float* wo   = (const float*)d_in[9];
    const float* bo   = (const float*)d_in[10];
    float* out = (float*)d_out;

    char* ws = (char*)d_ws;
    size_t off = 0;
    auto alloc = [&](size_t bytes) { char* p = ws + off; off += (bytes + 255) & ~(size_t)255; return p; };

    unsigned short* Xb   = (unsigned short*)alloc((size_t)ROWS * DIMN * 2);
    unsigned short* Wcat = (unsigned short*)alloc((size_t)NQKV * DIMN * 2);
    unsigned short* Wo   = (unsigned short*)alloc((size_t)DIMN * DIMN * 2);
    unsigned short* QKV  = (unsigned short*)alloc((size_t)ROWS * NQKV * 2);
    unsigned short* attn = (unsigned short*)alloc((size_t)ROWS * DIMN * 2);
    float*          part = (float*)alloc((size_t)32 * 8 * HD * HD * 4);
    unsigned short* M2   = (unsigned short*)alloc((size_t)32 * HD * HD * 2);

    // converts (weights concatenated into Wcat rows: [Wq; Wk; Wv])
    cvt_kernel<<<(ROWS * DIMN / 4 + 255) / 256, 256, 0, stream>>>(x, Xb, ROWS * DIMN);
    cvt_kernel<<<(DIMN * DIMN / 4 + 255) / 256, 256, 0, stream>>>(wq, Wcat, DIMN * DIMN);
    cvt_kernel<<<(DIMN * DIMN / 4 + 255) / 256, 256, 0, stream>>>(wk, Wcat + (size_t)DIMN * DIMN, DIMN * DIMN);
    cvt_kernel<<<(DIMN * DIMN / 4 + 255) / 256, 256, 0, stream>>>(wv, Wcat + (size_t)2 * DIMN * DIMN, DIMN * DIMN);
    cvt_kernel<<<(DIMN * DIMN / 4 + 255) / 256, 256, 0, stream>>>(wo, Wo, DIMN * DIMN);

    // fused QKV projection + bias + RoPE  (M=4096, N=6144, K=2048): 24x32 = 768 blocks (3 full rounds)
    gemm_p3<0><<<dim3(NQKV / 256, ROWS / 128), 512, 0, stream>>>(
        Xb, DIMN, Wcat, DIMN, bq, bk, bv, fcos, fsin, QKV, NQKV, DIMN);

    // reassociated attention (no softmax): M2 = (K^T V)/sqrt(d) per (b,h)
    ktv_kernel<<<dim3(8, 32), 256, 0, stream>>>(QKV, part);
    ktv_reduce<<<(32 * 16384) / 256, 256, 0, stream>>>(part, M2);

    // attn = Q @ M2^T per head
    qm_gemm<<<dim3(32, 16), 256, 0, stream>>>(QKV, M2, attn);

    // out = attn @ Wo^T + bo  (M=4096, N=2048, K=2048): 8x32 = 256 blocks (1 full round)
    gemm_p3<1><<<dim3(DIMN / 256, ROWS / 128), 512, 0, stream>>>(
        attn, DIMN, Wo, DIMN, bo, nullptr, nullptr, nullptr, nullptr, out, DIMN, DIMN);
}